// Round 20
// baseline (1196.862 us; speedup 1.0000x reference)
//
#include <hip/hip_runtime.h>
#include <hip/hip_bf16.h>

#define N_NODES 12288
#define D 256
#define NE 196608
#define TOPK 4
#define NBLK 96          // 12288 / 128 col-blocks
#define MAXDEG 256
// MEASURED (rounds 0-9): harness reads d_out as FLOAT32, identity layout:
// [ h 3145728 | top_idx 49152 | rows 49152 | top_vals 49152 ].

typedef __attribute__((ext_vector_type(8))) short bf8;     // 8 bf16 (4 VGPR)
typedef __attribute__((ext_vector_type(4))) float f32x4;   // MFMA 16x16 acc

// ---------------- insert helpers ----------------
__device__ __forceinline__ void ins4(float v, int id, float tv[TOPK], int ti[TOPK]) {
  if (v > tv[3]) {
    tv[3] = v; ti[3] = id;
    if (tv[3] > tv[2]) {
      float a = tv[2]; tv[2] = tv[3]; tv[3] = a; int b = ti[2]; ti[2] = ti[3]; ti[3] = b;
      if (tv[2] > tv[1]) {
        float a2 = tv[1]; tv[1] = tv[2]; tv[2] = a2; int b2 = ti[1]; ti[1] = ti[2]; ti[2] = b2;
        if (tv[1] > tv[0]) {
          float a3 = tv[0]; tv[0] = tv[1]; tv[1] = a3; int b3 = ti[0]; ti[0] = ti[1]; ti[1] = b3;
        }
      }
    }
  }
}

__device__ __forceinline__ void ins4tie(float v, int id, float tv[TOPK], int ti[TOPK]) {
  if ((v > tv[3]) || (v == tv[3] && id < ti[3])) {
    tv[3] = v; ti[3] = id;
    if ((tv[3] > tv[2]) || (tv[3] == tv[2] && ti[3] < ti[2])) {
      float a = tv[2]; tv[2] = tv[3]; tv[3] = a; int b = ti[2]; ti[2] = ti[3]; ti[3] = b;
      if ((tv[2] > tv[1]) || (tv[2] == tv[1] && ti[2] < ti[1])) {
        float a2 = tv[1]; tv[1] = tv[2]; tv[2] = a2; int b2 = ti[1]; ti[1] = ti[2]; ti[2] = b2;
        if ((tv[1] > tv[0]) || (tv[1] == tv[0] && ti[1] < ti[0])) {
          float a3 = tv[0]; tv[0] = tv[1]; tv[1] = a3; int b3 = ti[0]; ti[0] = ti[1]; ti[1] = b3;
        }
      }
    }
  }
}

__device__ __forceinline__ void ins8tie(float v, int id, float tv[8], int ti8[8]) {
  if (!((v > tv[7]) || (v == tv[7] && id < ti8[7]))) return;
  tv[7] = v; ti8[7] = id;
#pragma unroll
  for (int k = 7; k > 0; --k) {
    bool sw = (tv[k] > tv[k - 1]) || (tv[k] == tv[k - 1] && ti8[k] < ti8[k - 1]);
    if (sw) {
      float a = tv[k - 1]; tv[k - 1] = tv[k]; tv[k] = a;
      int b = ti8[k - 1]; ti8[k - 1] = ti8[k]; ti8[k] = b;
    }
  }
}

// ---------------- K1: XW = x @ W ----------------
__global__ __launch_bounds__(256) void k_xw(const float* __restrict__ X,
                                            const float* __restrict__ W,
                                            float* __restrict__ XW) {
  __shared__ float sA[16][65];
  __shared__ float sB[16][65];
  const int tid = threadIdx.x;
  const int ty = tid >> 4, tx = tid & 15;
  const int by = blockIdx.x, bx = blockIdx.y;
  float acc[4][4] = {};
  for (int kk = 0; kk < D; kk += 16) {
    {
      int m = tid >> 2;
      int kq = (tid & 3) << 2;
      const float4 av = *(const float4*)&X[(size_t)(by * 64 + m) * D + kk + kq];
      sA[kq + 0][m] = av.x; sA[kq + 1][m] = av.y; sA[kq + 2][m] = av.z; sA[kq + 3][m] = av.w;
    }
    {
      int r = tid >> 4;
      int c = (tid & 15) << 2;
      const float4 bv = *(const float4*)&W[(size_t)(kk + r) * D + bx * 64 + c];
      sB[r][c + 0] = bv.x; sB[r][c + 1] = bv.y; sB[r][c + 2] = bv.z; sB[r][c + 3] = bv.w;
    }
    __syncthreads();
#pragma unroll
    for (int k = 0; k < 16; ++k) {
      float a[4], b[4];
#pragma unroll
      for (int i = 0; i < 4; i++) a[i] = sA[k][ty + 16 * i];
#pragma unroll
      for (int j = 0; j < 4; j++) b[j] = sB[k][tx + 16 * j];
#pragma unroll
      for (int i = 0; i < 4; i++)
#pragma unroll
        for (int j = 0; j < 4; j++) acc[i][j] = fmaf(a[i], b[j], acc[i][j]);
    }
    __syncthreads();
  }
#pragma unroll
  for (int i = 0; i < 4; i++)
#pragma unroll
    for (int j = 0; j < 4; j++)
      XW[(size_t)(by * 64 + ty + 16 * i) * D + bx * 64 + tx + 16 * j] = acc[i][j];
}

// ---------------- K2: in-degree histogram ----------------
__global__ void k_deg(const int* __restrict__ row, int* __restrict__ deg) {
  int e = blockIdx.x * blockDim.x + threadIdx.x;
  if (e < NE) {
    unsigned r = (unsigned)row[e];
    if (r < N_NODES) atomicAdd(&deg[r], 1);
  }
}

// ---------------- K3: exclusive scan + dinv ----------------
__global__ __launch_bounds__(256) void k_scan(const int* __restrict__ deg,
                                              int* __restrict__ row_start,
                                              float* __restrict__ dinv) {
  __shared__ int part[256];
  const int tid = threadIdx.x;
  const int L = N_NODES / 256;  // 48
  const int base = tid * L;
  int s = 0;
  for (int i = 0; i < L; i++) s += deg[base + i];
  part[tid] = s;
  __syncthreads();
  for (int off = 1; off < 256; off <<= 1) {
    int v = (tid >= off) ? part[tid - off] : 0;
    __syncthreads();
    part[tid] += v;
    __syncthreads();
  }
  int run = part[tid] - s;
  for (int i = 0; i < L; i++) {
    int d = deg[base + i];
    row_start[base + i] = run;
    dinv[base + i] = 1.0f / sqrtf((float)(d + 1));
    run += d;
  }
}

// ---------------- K4: CSR fill ----------------
__global__ void k_fill(const int* __restrict__ row, const int* __restrict__ col,
                       const int* __restrict__ row_start, int* __restrict__ cursor,
                       int* __restrict__ ecol, int* __restrict__ eeid) {
  int e = blockIdx.x * blockDim.x + threadIdx.x;
  if (e >= NE) return;
  unsigned r = (unsigned)row[e];
  if (r >= N_NODES) return;
  int p = atomicAdd(&cursor[r], 1);
  int slot = row_start[r] + p;
  if ((unsigned)slot >= NE) return;
  unsigned c = (unsigned)col[e];
  if (c >= N_NODES) c = 0;
  ecol[slot] = (int)c;
  eeid[slot] = e;
}

// ---------------- K5: aggregation (eid-sorted -> deterministic); h -> d_out ------
__global__ __launch_bounds__(256) void k_agg(const float* __restrict__ XW,
                                             const float* __restrict__ bias,
                                             const int* __restrict__ deg,
                                             const int* __restrict__ row_start,
                                             const int* __restrict__ ecol,
                                             const int* __restrict__ eeid,
                                             const float* __restrict__ dinv,
                                             float* __restrict__ h_out,
                                             float* __restrict__ sq) {
  __shared__ int sc[MAXDEG];
  __shared__ int se[MAXDEG];
  __shared__ float snorm[MAXDEG];
  __shared__ float red[256];
  const int i = blockIdx.x;
  const int tid = threadIdx.x;
  int cnt = deg[i];
  if (cnt > MAXDEG) cnt = MAXDEG;
  if (cnt < 0) cnt = 0;
  const int st = row_start[i];
  for (int t = tid; t < cnt; t += 256) {
    unsigned cc = (unsigned)ecol[st + t];
    sc[t] = (cc < N_NODES) ? (int)cc : 0;
    se[t] = eeid[st + t];
  }
  __syncthreads();
  if (tid == 0) {  // insertion sort by original edge id
    for (int a = 1; a < cnt; ++a) {
      int ce = se[a], cc = sc[a];
      int bp = a - 1;
      while (bp >= 0 && se[bp] > ce) { se[bp + 1] = se[bp]; sc[bp + 1] = sc[bp]; --bp; }
      se[bp + 1] = ce; sc[bp + 1] = cc;
    }
  }
  __syncthreads();
  const float di = dinv[i];
  for (int t = tid; t < cnt; t += 256) snorm[t] = __fmul_rn(di, dinv[sc[t]]);
  __syncthreads();
  float acc = 0.0f;
  for (int t = 0; t < cnt; ++t) {
    float v = XW[(size_t)sc[t] * D + tid];
    acc = __fadd_rn(acc, __fmul_rn(v, snorm[t]));
  }
  acc = __fadd_rn(acc, __fmul_rn(XW[(size_t)i * D + tid], __fmul_rn(di, di)));  // self loop last
  acc = __fadd_rn(acc, bias[tid]);
  h_out[(size_t)i * D + tid] = acc;
  red[tid] = __fmul_rn(acc, acc);
  __syncthreads();
  for (int off = 128; off > 0; off >>= 1) {
    if (tid < off) red[tid] = __fadd_rn(red[tid], red[tid + off]);
    __syncthreads();
  }
  if (tid == 0) sq[i] = red[0];
}

// ---------------- K6: h -> (hi, lo) bf16 split ----------------
__global__ __launch_bounds__(256) void k_split(const float* __restrict__ h,
                                               unsigned short* __restrict__ hhi,
                                               unsigned short* __restrict__ hlo) {
  int i = blockIdx.x * 256 + threadIdx.x;  // grid = N*D/256
  float v = h[i];
  __hip_bfloat16 bh = __float2bfloat16(v);
  float hiF = __bfloat162float(bh);
  __hip_bfloat16 bl = __float2bfloat16(v - hiF);
  hhi[i] = *(unsigned short*)&bh;
  hlo[i] = *(unsigned short*)&bl;
}

// ---------------- K7 v4: MFMA GEMM, small-LDS two-phase scan (4 blocks/CU) ------
// r19 diagnosis: latency-bound at 2 blocks/CU (LDS 68 KB cap); explicit ILP
// pipeline defeated by 128-VGPR choice. v4: lq computed IN-PLACE into acc,
// LDS shrunk to [128][69] f32 (35.3 KB, stride 69 = 2-way-free banks) with
// a two-phase dump+scan (waves 0-1 dump cols 0-63, scan; waves 2-3 dump cols
// 64-127, scan) -> 4 blocks/CU = 4 waves/SIMD for latency hiding.
// Candidate semantics identical to r16-18 (same ins4 set, exact rerank after).
__global__ __launch_bounds__(256, 4) void k_gemm(const unsigned short* __restrict__ hhi,
                                                 const unsigned short* __restrict__ hlo,
                                                 const float* __restrict__ sq,
                                                 const float* __restrict__ q,
                                                 const float* __restrict__ tempP,
                                                 float* __restrict__ candv,
                                                 int* __restrict__ candi) {
  __shared__ float lqs[128][69];   // 35.3 KB -> 4 blocks/CU
  const int tid = threadIdx.x;
  const int w = tid >> 6, l = tid & 63;
  const int row0 = blockIdx.x * 128, col0 = blockIdx.y * 128;
  const float T = tempP[0];

  f32x4 acc[4][4];
#pragma unroll
  for (int a = 0; a < 4; ++a)
#pragma unroll
    for (int b = 0; b < 4; ++b) acc[a][b] = (f32x4){0.f, 0.f, 0.f, 0.f};

  const int koct = l >> 4;                       // k-octet 0..3 (8 bf16 each)
  const int arow = row0 + (w & 1) * 64 + (l & 15);
  const int brow = col0 + (w >> 1) * 64 + (l & 15);
  const unsigned short* Ah0 = hhi + (size_t)arow * D + koct * 8;
  const unsigned short* Al0 = hlo + (size_t)arow * D + koct * 8;
  const unsigned short* Bh0 = hhi + (size_t)brow * D + koct * 8;
  const unsigned short* Bl0 = hlo + (size_t)brow * D + koct * 8;

  for (int kc = 0; kc < D; kc += 32) {  // 8 K-chunks, no barriers (r18 form)
    bf8 Ah[4], Al[4], Bh[4], Bl[4];
#pragma unroll
    for (int a = 0; a < 4; ++a) {
      Ah[a] = *(const bf8*)(Ah0 + (size_t)a * 16 * D + kc);
      Al[a] = *(const bf8*)(Al0 + (size_t)a * 16 * D + kc);
      Bh[a] = *(const bf8*)(Bh0 + (size_t)a * 16 * D + kc);
      Bl[a] = *(const bf8*)(Bl0 + (size_t)a * 16 * D + kc);
    }
#pragma unroll
    for (int a = 0; a < 4; ++a)
#pragma unroll
      for (int b = 0; b < 4; ++b) {
        acc[a][b] = __builtin_amdgcn_mfma_f32_16x16x32_bf16(Ah[a], Bh[b], acc[a][b], 0, 0, 0);
        acc[a][b] = __builtin_amdgcn_mfma_f32_16x16x32_bf16(Ah[a], Bl[b], acc[a][b], 0, 0, 0);
        acc[a][b] = __builtin_amdgcn_mfma_f32_16x16x32_bf16(Al[a], Bh[b], acc[a][b], 0, 0, 0);
      }
  }

  // lq computed IN-PLACE into acc (coalesced q reads; C/D map col=lane&15,
  // row=(lane>>4)*4+reg)
#pragma unroll
  for (int a = 0; a < 4; ++a)
#pragma unroll
    for (int b = 0; b < 4; ++b)
#pragma unroll
      for (int r = 0; r < 4; ++r) {
        int rowblk = (w & 1) * 64 + a * 16 + (l >> 4) * 4 + r;
        int colblk = (w >> 1) * 64 + b * 16 + (l & 15);
        int grow = row0 + rowblk, gcol = col0 + colblk;
        float dot = acc[a][b][r];
        float d2 = fmaxf((sq[grow] + sq[gcol]) - 2.0f * dot, 0.0f);
        float gg = __logf(-__logf(q[(size_t)grow * N_NODES + gcol] + 1e-8f));
        acc[a][b][r] = -T * d2 - gg;
      }

  float tv[TOPK]; int ti4[TOPK];
#pragma unroll
  for (int k = 0; k < TOPK; ++k) { tv[k] = -3.0e38f; ti4[k] = 0; }
  const int rw = tid >> 1, cb = (tid & 1) * 32;

  // phase 0: waves 0,1 own cols [0,64) -> dump, all scan
  if ((w >> 1) == 0) {
#pragma unroll
    for (int a = 0; a < 4; ++a)
#pragma unroll
      for (int b = 0; b < 4; ++b)
#pragma unroll
        for (int r = 0; r < 4; ++r) {
          int rowblk = (w & 1) * 64 + a * 16 + (l >> 4) * 4 + r;
          int colblk = b * 16 + (l & 15);
          lqs[rowblk][colblk] = acc[a][b][r];
        }
  }
  __syncthreads();
  for (int i = 0; i < 32; ++i) ins4(lqs[rw][cb + i], col0 + cb + i, tv, ti4);
  __syncthreads();
  // phase 1: waves 2,3 own cols [64,128) -> dump, all scan
  if ((w >> 1) == 1) {
#pragma unroll
    for (int a = 0; a < 4; ++a)
#pragma unroll
      for (int b = 0; b < 4; ++b)
#pragma unroll
        for (int r = 0; r < 4; ++r) {
          int rowblk = (w & 1) * 64 + a * 16 + (l >> 4) * 4 + r;
          int colblk = b * 16 + (l & 15);   // global col = col0+64+colblk
          lqs[rowblk][colblk] = acc[a][b][r];
        }
  }
  __syncthreads();
  for (int i = 0; i < 32; ++i) ins4(lqs[rw][cb + i], col0 + 64 + cb + i, tv, ti4);

  // snapshot pair-merge (t ^ 1 covers the other 32-col half of both phases)
  float ov[TOPK]; int oi[TOPK];
#pragma unroll
  for (int k = 0; k < TOPK; ++k) {
    ov[k] = __shfl_xor(tv[k], 1);
    oi[k] = __shfl_xor(ti4[k], 1);
  }
#pragma unroll
  for (int k = 0; k < TOPK; ++k) ins4tie(ov[k], oi[k], tv, ti4);
  if ((tid & 1) == 0) {
    size_t base = ((size_t)(row0 + rw) * NBLK + blockIdx.y) * TOPK;
#pragma unroll
    for (int k = 0; k < TOPK; ++k) { candv[base + k] = tv[k]; candi[base + k] = ti4[k]; }
  }
}

// ---------------- K8a: per-(row, chunk-of-48) serial top-8 (pure TLP) ----------
__global__ __launch_bounds__(256) void k_cmerge1(const float* __restrict__ candv,
                                                 const int* __restrict__ candi,
                                                 float* __restrict__ pv8,
                                                 int* __restrict__ pi8) {
  int gid = blockIdx.x * 256 + threadIdx.x;      // [0, 12288*8)
  int row = gid >> 3, chunk = gid & 7;
  size_t base = (size_t)row * (NBLK * TOPK) + chunk * 48;
  float tv[8]; int ti8[8];
#pragma unroll
  for (int k = 0; k < 8; ++k) { tv[k] = -3.0e38f; ti8[k] = 0; }
  for (int i = 0; i < 48; ++i) ins8tie(candv[base + i], candi[base + i], tv, ti8);
  size_t ob = (size_t)gid * 8;
#pragma unroll
  for (int k = 0; k < 8; ++k) { pv8[ob + k] = tv[k]; pi8[ob + k] = ti8[k]; }
}

// ---------------- K8b: per-row merge of 8 partials + self-sentinel -------------
__global__ __launch_bounds__(256) void k_cmerge2(const float* __restrict__ pv8,
                                                 const int* __restrict__ pi8,
                                                 float* __restrict__ fv8,
                                                 int* __restrict__ fi8) {
  int row = blockIdx.x * 256 + threadIdx.x;      // [0, 12288)
  size_t base = (size_t)row * 64;
  float tv[8]; int ti8[8];
#pragma unroll
  for (int k = 0; k < 8; ++k) { tv[k] = -3.0e38f; ti8[k] = 0; }
  for (int i = 0; i < 64; ++i) ins8tie(pv8[base + i], pi8[base + i], tv, ti8);
  ins8tie(3.0e38f, row, tv, ti8);                // self-sentinel
  size_t ob = (size_t)row * 8;
#pragma unroll
  for (int k = 0; k < 8; ++k) { fv8[ob + k] = tv[k]; fi8[ob + k] = ti8[k]; }
}

// ---------------- K8c: exact fp32 rerank of final 8 (one wave per row) ---------
__global__ __launch_bounds__(256) void k_exact(const int* __restrict__ fi8,
                                               const float* __restrict__ h,
                                               const float* __restrict__ sq,
                                               const float* __restrict__ q,
                                               const float* __restrict__ tempP,
                                               float* __restrict__ out_idx,
                                               float* __restrict__ out_rows,
                                               float* __restrict__ out_vals) {
  const int tid = threadIdx.x;
  const int row = blockIdx.x * 4 + (tid >> 6);
  const int l = tid & 63;
  const float T = tempP[0];
  int ti8[8];
#pragma unroll
  for (int k = 0; k < 8; ++k) ti8[k] = fi8[(size_t)row * 8 + k];
  float4 hr = *(const float4*)&h[(size_t)row * D + l * 4];
  float lqe[8];
#pragma unroll
  for (int k = 0; k < 8; ++k) {
    int c = ti8[k];
    float4 hc = *(const float4*)&h[(size_t)c * D + l * 4];
    float p = fmaf(hr.x, hc.x, 0.0f);
    p = fmaf(hr.y, hc.y, p);
    p = fmaf(hr.z, hc.z, p);
    p = fmaf(hr.w, hc.w, p);
#pragma unroll
    for (int m = 1; m < 64; m <<= 1) p += __shfl_xor(p, m);
    float d2 = fmaxf(__fsub_rn(__fadd_rn(sq[row], sq[c]), __fmul_rn(2.0f, p)), 0.0f);
    float lp = -__fmul_rn(T, d2);
    float gg = logf(-logf(__fadd_rn(q[(size_t)row * N_NODES + c], 1e-8f)));
    lqe[k] = __fsub_rn(lp, gg);
  }
  float bv[TOPK]; int bi[TOPK];
#pragma unroll
  for (int k = 0; k < TOPK; ++k) { bv[k] = -3.0e38f; bi[k] = 0; }
#pragma unroll
  for (int k = 0; k < 8; ++k) {   // dedupe guard (sentinel + organic self)
    bool dup = false;
#pragma unroll
    for (int k2 = 0; k2 < 8; ++k2)
      if (k2 < k) dup = dup || (ti8[k2] == ti8[k]);
    if (!dup) ins4tie(lqe[k], ti8[k], bv, bi);
  }
  if (l == 0) {
#pragma unroll
    for (int k = 0; k < TOPK; ++k) {
      out_idx[(size_t)row * TOPK + k] = (float)bi[k];
      out_rows[(size_t)row * TOPK + k] = (float)row;
      out_vals[(size_t)row * TOPK + k] = bv[k];
    }
  }
}

// ---------------- launcher ----------------
extern "C" void kernel_launch(void* const* d_in, const int* in_sizes, int n_in,
                              void* d_out, int out_size, void* d_ws, size_t ws_size,
                              hipStream_t stream) {
  const float* x = nullptr;     // 3145728
  const float* W = nullptr;     // 65536
  const float* b = nullptr;     // 256
  const float* temp = nullptr;  // 1
  const float* q = nullptr;     // 150994944
  const int* ei = nullptr;      // 393216
  for (int i = 0; i < n_in; ++i) {
    switch (in_sizes[i]) {
      case 3145728:   x = (const float*)d_in[i]; break;
      case 65536:     W = (const float*)d_in[i]; break;
      case 256:       b = (const float*)d_in[i]; break;
      case 1:         temp = (const float*)d_in[i]; break;
      case 150994944: q = (const float*)d_in[i]; break;
      case 393216:    ei = (const int*)d_in[i]; break;
      default: break;
    }
  }
  if (!x || !W || !b || !temp || !q || !ei) return;

  float* out = (float*)d_out;
  float* out_h = out;                                  // [0, 3145728)
  float* out_idx = out + (size_t)N_NODES * D;          // [3145728, 3194880)
  float* out_rows = out_idx + (size_t)N_NODES * TOPK;  // [3194880, 3244032)
  float* out_vals = out_rows + (size_t)N_NODES * TOPK; // [3244032, 3293184)

  char* ws = (char*)d_ws;
  size_t off = 0;
  auto alloc = [&](size_t bytes) {
    char* p = ws + off;
    off += (bytes + 255) & ~(size_t)255;
    return p;
  };
  float* XW = (float*)alloc((size_t)N_NODES * D * 4);  // reused as hhi/hlo after k_agg
  int* deg = (int*)alloc((size_t)N_NODES * 4);
  int* rs = (int*)alloc((size_t)N_NODES * 4);
  int* cur = (int*)alloc((size_t)N_NODES * 4);
  float* dinv = (float*)alloc((size_t)N_NODES * 4);
  float* sq = (float*)alloc((size_t)N_NODES * 4);
  int* ecol = (int*)alloc((size_t)NE * 4);
  int* eeid = (int*)alloc((size_t)NE * 4);
  float* candv = (float*)alloc((size_t)N_NODES * NBLK * TOPK * 4);  // 18.9 MB
  int* candi = (int*)alloc((size_t)N_NODES * NBLK * TOPK * 4);      // 18.9 MB
  float* pv8 = (float*)alloc((size_t)N_NODES * 64 * 4);             // 3.1 MB
  int* pi8 = (int*)alloc((size_t)N_NODES * 64 * 4);                 // 3.1 MB
  float* fv8 = (float*)alloc((size_t)N_NODES * 8 * 4);              // 0.4 MB
  int* fi8 = (int*)alloc((size_t)N_NODES * 8 * 4);                  // 0.4 MB
  if (off > ws_size) return;  // loud zero-output beacon if ws too small

  hipMemsetAsync(deg, 0, (size_t)N_NODES * 4, stream);
  hipMemsetAsync(cur, 0, (size_t)N_NODES * 4, stream);

  k_xw<<<dim3(N_NODES / 64, D / 64), 256, 0, stream>>>(x, W, XW);
  k_deg<<<NE / 256, 256, 0, stream>>>(ei, deg);
  k_scan<<<1, 256, 0, stream>>>(deg, rs, dinv);
  k_fill<<<NE / 256, 256, 0, stream>>>(ei, ei + NE, rs, cur, ecol, eeid);
  k_agg<<<N_NODES, 256, 0, stream>>>(XW, b, deg, rs, ecol, eeid, dinv, out_h, sq);

  // XW dead -> reuse as bf16 hi/lo arrays (exact fit: N*D*2B*2 = N*D*4B)
  unsigned short* hhi = (unsigned short*)XW;
  unsigned short* hlo = hhi + (size_t)N_NODES * D;
  k_split<<<(N_NODES * D) / 256, 256, 0, stream>>>(out_h, hhi, hlo);
  k_gemm<<<dim3(NBLK, NBLK), 256, 0, stream>>>(hhi, hlo, sq, q, temp, candv, candi);
  k_cmerge1<<<(N_NODES * 8) / 256, 256, 0, stream>>>(candv, candi, pv8, pi8);
  k_cmerge2<<<N_NODES / 256, 256, 0, stream>>>(pv8, pi8, fv8, fi8);
  k_exact<<<N_NODES / 4, 256, 0, stream>>>(fi8, out_h, sq, q, temp,
                                           out_idx, out_rows, out_vals);
}

// Round 21
// 1051.308 us; speedup vs baseline: 1.1384x; 1.1384x over previous
//
#include <hip/hip_runtime.h>
#include <hip/hip_bf16.h>

#define N_NODES 12288
#define D 256
#define NE 196608
#define TOPK 4
#define NBLK 96          // 12288 / 128 col-blocks
#define MAXDEG 256
// MEASURED (rounds 0-9): harness reads d_out as FLOAT32, identity layout:
// [ h 3145728 | top_idx 49152 | rows 49152 | top_vals 49152 ].

typedef __attribute__((ext_vector_type(8))) short bf8;     // 8 bf16 (4 VGPR)
typedef __attribute__((ext_vector_type(4))) float f32x4;   // MFMA 16x16 acc

// ---------------- insert helpers ----------------
__device__ __forceinline__ void ins4(float v, int id, float tv[TOPK], int ti[TOPK]) {
  if (v > tv[3]) {
    tv[3] = v; ti[3] = id;
    if (tv[3] > tv[2]) {
      float a = tv[2]; tv[2] = tv[3]; tv[3] = a; int b = ti[2]; ti[2] = ti[3]; ti[3] = b;
      if (tv[2] > tv[1]) {
        float a2 = tv[1]; tv[1] = tv[2]; tv[2] = a2; int b2 = ti[1]; ti[1] = ti[2]; ti[2] = b2;
        if (tv[1] > tv[0]) {
          float a3 = tv[0]; tv[0] = tv[1]; tv[1] = a3; int b3 = ti[0]; ti[0] = ti[1]; ti[1] = b3;
        }
      }
    }
  }
}

__device__ __forceinline__ void ins4tie(float v, int id, float tv[TOPK], int ti[TOPK]) {
  if ((v > tv[3]) || (v == tv[3] && id < ti[3])) {
    tv[3] = v; ti[3] = id;
    if ((tv[3] > tv[2]) || (tv[3] == tv[2] && ti[3] < ti[2])) {
      float a = tv[2]; tv[2] = tv[3]; tv[3] = a; int b = ti[2]; ti[2] = ti[3]; ti[3] = b;
      if ((tv[2] > tv[1]) || (tv[2] == tv[1] && ti[2] < ti[1])) {
        float a2 = tv[1]; tv[1] = tv[2]; tv[2] = a2; int b2 = ti[1]; ti[1] = ti[2]; ti[2] = b2;
        if ((tv[1] > tv[0]) || (tv[1] == tv[0] && ti[1] < ti[0])) {
          float a3 = tv[0]; tv[0] = tv[1]; tv[1] = a3; int b3 = ti[0]; ti[0] = ti[1]; ti[1] = b3;
        }
      }
    }
  }
}

__device__ __forceinline__ void ins8tie(float v, int id, float tv[8], int ti8[8]) {
  if (!((v > tv[7]) || (v == tv[7] && id < ti8[7]))) return;
  tv[7] = v; ti8[7] = id;
#pragma unroll
  for (int k = 7; k > 0; --k) {
    bool sw = (tv[k] > tv[k - 1]) || (tv[k] == tv[k - 1] && ti8[k] < ti8[k - 1]);
    if (sw) {
      float a = tv[k - 1]; tv[k - 1] = tv[k]; tv[k] = a;
      int b = ti8[k - 1]; ti8[k - 1] = ti8[k]; ti8[k] = b;
    }
  }
}

// ---------------- K1: XW = x @ W ----------------
__global__ __launch_bounds__(256) void k_xw(const float* __restrict__ X,
                                            const float* __restrict__ W,
                                            float* __restrict__ XW) {
  __shared__ float sA[16][65];
  __shared__ float sB[16][65];
  const int tid = threadIdx.x;
  const int ty = tid >> 4, tx = tid & 15;
  const int by = blockIdx.x, bx = blockIdx.y;
  float acc[4][4] = {};
  for (int kk = 0; kk < D; kk += 16) {
    {
      int m = tid >> 2;
      int kq = (tid & 3) << 2;
      const float4 av = *(const float4*)&X[(size_t)(by * 64 + m) * D + kk + kq];
      sA[kq + 0][m] = av.x; sA[kq + 1][m] = av.y; sA[kq + 2][m] = av.z; sA[kq + 3][m] = av.w;
    }
    {
      int r = tid >> 4;
      int c = (tid & 15) << 2;
      const float4 bv = *(const float4*)&W[(size_t)(kk + r) * D + bx * 64 + c];
      sB[r][c + 0] = bv.x; sB[r][c + 1] = bv.y; sB[r][c + 2] = bv.z; sB[r][c + 3] = bv.w;
    }
    __syncthreads();
#pragma unroll
    for (int k = 0; k < 16; ++k) {
      float a[4], b[4];
#pragma unroll
      for (int i = 0; i < 4; i++) a[i] = sA[k][ty + 16 * i];
#pragma unroll
      for (int j = 0; j < 4; j++) b[j] = sB[k][tx + 16 * j];
#pragma unroll
      for (int i = 0; i < 4; i++)
#pragma unroll
        for (int j = 0; j < 4; j++) acc[i][j] = fmaf(a[i], b[j], acc[i][j]);
    }
    __syncthreads();
  }
#pragma unroll
  for (int i = 0; i < 4; i++)
#pragma unroll
    for (int j = 0; j < 4; j++)
      XW[(size_t)(by * 64 + ty + 16 * i) * D + bx * 64 + tx + 16 * j] = acc[i][j];
}

// ---------------- K2: in-degree histogram ----------------
__global__ void k_deg(const int* __restrict__ row, int* __restrict__ deg) {
  int e = blockIdx.x * blockDim.x + threadIdx.x;
  if (e < NE) {
    unsigned r = (unsigned)row[e];
    if (r < N_NODES) atomicAdd(&deg[r], 1);
  }
}

// ---------------- K3: exclusive scan + dinv ----------------
__global__ __launch_bounds__(256) void k_scan(const int* __restrict__ deg,
                                              int* __restrict__ row_start,
                                              float* __restrict__ dinv) {
  __shared__ int part[256];
  const int tid = threadIdx.x;
  const int L = N_NODES / 256;  // 48
  const int base = tid * L;
  int s = 0;
  for (int i = 0; i < L; i++) s += deg[base + i];
  part[tid] = s;
  __syncthreads();
  for (int off = 1; off < 256; off <<= 1) {
    int v = (tid >= off) ? part[tid - off] : 0;
    __syncthreads();
    part[tid] += v;
    __syncthreads();
  }
  int run = part[tid] - s;
  for (int i = 0; i < L; i++) {
    int d = deg[base + i];
    row_start[base + i] = run;
    dinv[base + i] = 1.0f / sqrtf((float)(d + 1));
    run += d;
  }
}

// ---------------- K4: CSR fill ----------------
__global__ void k_fill(const int* __restrict__ row, const int* __restrict__ col,
                       const int* __restrict__ row_start, int* __restrict__ cursor,
                       int* __restrict__ ecol, int* __restrict__ eeid) {
  int e = blockIdx.x * blockDim.x + threadIdx.x;
  if (e >= NE) return;
  unsigned r = (unsigned)row[e];
  if (r >= N_NODES) return;
  int p = atomicAdd(&cursor[r], 1);
  int slot = row_start[r] + p;
  if ((unsigned)slot >= NE) return;
  unsigned c = (unsigned)col[e];
  if (c >= N_NODES) c = 0;
  ecol[slot] = (int)c;
  eeid[slot] = e;
}

// ---------------- K5: aggregation (eid-sorted -> deterministic); h -> d_out ------
__global__ __launch_bounds__(256) void k_agg(const float* __restrict__ XW,
                                             const float* __restrict__ bias,
                                             const int* __restrict__ deg,
                                             const int* __restrict__ row_start,
                                             const int* __restrict__ ecol,
                                             const int* __restrict__ eeid,
                                             const float* __restrict__ dinv,
                                             float* __restrict__ h_out,
                                             float* __restrict__ sq) {
  __shared__ int sc[MAXDEG];
  __shared__ int se[MAXDEG];
  __shared__ float snorm[MAXDEG];
  __shared__ float red[256];
  const int i = blockIdx.x;
  const int tid = threadIdx.x;
  int cnt = deg[i];
  if (cnt > MAXDEG) cnt = MAXDEG;
  if (cnt < 0) cnt = 0;
  const int st = row_start[i];
  for (int t = tid; t < cnt; t += 256) {
    unsigned cc = (unsigned)ecol[st + t];
    sc[t] = (cc < N_NODES) ? (int)cc : 0;
    se[t] = eeid[st + t];
  }
  __syncthreads();
  if (tid == 0) {  // insertion sort by original edge id
    for (int a = 1; a < cnt; ++a) {
      int ce = se[a], cc = sc[a];
      int bp = a - 1;
      while (bp >= 0 && se[bp] > ce) { se[bp + 1] = se[bp]; sc[bp + 1] = sc[bp]; --bp; }
      se[bp + 1] = ce; sc[bp + 1] = cc;
    }
  }
  __syncthreads();
  const float di = dinv[i];
  for (int t = tid; t < cnt; t += 256) snorm[t] = __fmul_rn(di, dinv[sc[t]]);
  __syncthreads();
  float acc = 0.0f;
  for (int t = 0; t < cnt; ++t) {
    float v = XW[(size_t)sc[t] * D + tid];
    acc = __fadd_rn(acc, __fmul_rn(v, snorm[t]));
  }
  acc = __fadd_rn(acc, __fmul_rn(XW[(size_t)i * D + tid], __fmul_rn(di, di)));  // self loop last
  acc = __fadd_rn(acc, bias[tid]);
  h_out[(size_t)i * D + tid] = acc;
  red[tid] = __fmul_rn(acc, acc);
  __syncthreads();
  for (int off = 128; off > 0; off >>= 1) {
    if (tid < off) red[tid] = __fadd_rn(red[tid], red[tid + off]);
    __syncthreads();
  }
  if (tid == 0) sq[i] = red[0];
}

// ---------------- K6: h -> (hi, lo) bf16 split ----------------
__global__ __launch_bounds__(256) void k_split(const float* __restrict__ h,
                                               unsigned short* __restrict__ hhi,
                                               unsigned short* __restrict__ hlo) {
  int i = blockIdx.x * 256 + threadIdx.x;  // grid = N*D/256
  float v = h[i];
  __hip_bfloat16 bh = __float2bfloat16(v);
  float hiF = __bfloat162float(bh);
  __hip_bfloat16 bl = __float2bfloat16(v - hiF);
  hhi[i] = *(unsigned short*)&bh;
  hlo[i] = *(unsigned short*)&bl;
}

// ---------------- K7 v5: MFMA GEMM, small-LDS + natural VGPR (4 blocks/CU) ------
// r20 post-mortem: launch_bounds(256,4) forced VGPR=64 -> acc[4][4] f32x4 (64
// VGPRs) spilled to scratch (WRITE_SIZE 160 KB -> 598 MB, hbm 1.5 GB). v5 keeps
// r20's 35.3 KB LDS (4 blocks/CU) but restores launch_bounds(256,2): compiler
// picks ~128 VGPR (r18/r19 behavior) and 512/128 = 4 waves/SIMD fit anyway ->
// occupancy AND no spill. Candidate semantics identical to r16-r20.
__global__ __launch_bounds__(256, 2) void k_gemm(const unsigned short* __restrict__ hhi,
                                                 const unsigned short* __restrict__ hlo,
                                                 const float* __restrict__ sq,
                                                 const float* __restrict__ q,
                                                 const float* __restrict__ tempP,
                                                 float* __restrict__ candv,
                                                 int* __restrict__ candi) {
  __shared__ float lqs[128][69];   // 35.3 KB -> 4 blocks/CU (LDS-wise)
  const int tid = threadIdx.x;
  const int w = tid >> 6, l = tid & 63;
  const int row0 = blockIdx.x * 128, col0 = blockIdx.y * 128;
  const float T = tempP[0];

  f32x4 acc[4][4];
#pragma unroll
  for (int a = 0; a < 4; ++a)
#pragma unroll
    for (int b = 0; b < 4; ++b) acc[a][b] = (f32x4){0.f, 0.f, 0.f, 0.f};

  const int koct = l >> 4;                       // k-octet 0..3 (8 bf16 each)
  const int arow = row0 + (w & 1) * 64 + (l & 15);
  const int brow = col0 + (w >> 1) * 64 + (l & 15);
  const unsigned short* Ah0 = hhi + (size_t)arow * D + koct * 8;
  const unsigned short* Al0 = hlo + (size_t)arow * D + koct * 8;
  const unsigned short* Bh0 = hhi + (size_t)brow * D + koct * 8;
  const unsigned short* Bl0 = hlo + (size_t)brow * D + koct * 8;

  for (int kc = 0; kc < D; kc += 32) {  // 8 K-chunks, no barriers (r18 form)
    bf8 Ah[4], Al[4], Bh[4], Bl[4];
#pragma unroll
    for (int a = 0; a < 4; ++a) {
      Ah[a] = *(const bf8*)(Ah0 + (size_t)a * 16 * D + kc);
      Al[a] = *(const bf8*)(Al0 + (size_t)a * 16 * D + kc);
      Bh[a] = *(const bf8*)(Bh0 + (size_t)a * 16 * D + kc);
      Bl[a] = *(const bf8*)(Bl0 + (size_t)a * 16 * D + kc);
    }
#pragma unroll
    for (int a = 0; a < 4; ++a)
#pragma unroll
      for (int b = 0; b < 4; ++b) {
        acc[a][b] = __builtin_amdgcn_mfma_f32_16x16x32_bf16(Ah[a], Bh[b], acc[a][b], 0, 0, 0);
        acc[a][b] = __builtin_amdgcn_mfma_f32_16x16x32_bf16(Ah[a], Bl[b], acc[a][b], 0, 0, 0);
        acc[a][b] = __builtin_amdgcn_mfma_f32_16x16x32_bf16(Al[a], Bh[b], acc[a][b], 0, 0, 0);
      }
  }

  // lq computed IN-PLACE into acc (C/D map: col=lane&15, row=(lane>>4)*4+reg)
#pragma unroll
  for (int a = 0; a < 4; ++a)
#pragma unroll
    for (int b = 0; b < 4; ++b)
#pragma unroll
      for (int r = 0; r < 4; ++r) {
        int rowblk = (w & 1) * 64 + a * 16 + (l >> 4) * 4 + r;
        int colblk = (w >> 1) * 64 + b * 16 + (l & 15);
        int grow = row0 + rowblk, gcol = col0 + colblk;
        float dot = acc[a][b][r];
        float d2 = fmaxf((sq[grow] + sq[gcol]) - 2.0f * dot, 0.0f);
        float gg = __logf(-__logf(q[(size_t)grow * N_NODES + gcol] + 1e-8f));
        acc[a][b][r] = -T * d2 - gg;
      }

  float tv[TOPK]; int ti4[TOPK];
#pragma unroll
  for (int k = 0; k < TOPK; ++k) { tv[k] = -3.0e38f; ti4[k] = 0; }
  const int rw = tid >> 1, cb = (tid & 1) * 32;

  // phase 0: waves 0,1 own cols [0,64) -> dump, all scan
  if ((w >> 1) == 0) {
#pragma unroll
    for (int a = 0; a < 4; ++a)
#pragma unroll
      for (int b = 0; b < 4; ++b)
#pragma unroll
        for (int r = 0; r < 4; ++r) {
          int rowblk = (w & 1) * 64 + a * 16 + (l >> 4) * 4 + r;
          int colblk = b * 16 + (l & 15);
          lqs[rowblk][colblk] = acc[a][b][r];
        }
  }
  __syncthreads();
  for (int i = 0; i < 32; ++i) ins4(lqs[rw][cb + i], col0 + cb + i, tv, ti4);
  __syncthreads();
  // phase 1: waves 2,3 own cols [64,128) -> dump, all scan
  if ((w >> 1) == 1) {
#pragma unroll
    for (int a = 0; a < 4; ++a)
#pragma unroll
      for (int b = 0; b < 4; ++b)
#pragma unroll
        for (int r = 0; r < 4; ++r) {
          int rowblk = (w & 1) * 64 + a * 16 + (l >> 4) * 4 + r;
          int colblk = b * 16 + (l & 15);   // global col = col0+64+colblk
          lqs[rowblk][colblk] = acc[a][b][r];
        }
  }
  __syncthreads();
  for (int i = 0; i < 32; ++i) ins4(lqs[rw][cb + i], col0 + 64 + cb + i, tv, ti4);

  // snapshot pair-merge (t ^ 1 covers the other 32-col half of both phases)
  float ov[TOPK]; int oi[TOPK];
#pragma unroll
  for (int k = 0; k < TOPK; ++k) {
    ov[k] = __shfl_xor(tv[k], 1);
    oi[k] = __shfl_xor(ti4[k], 1);
  }
#pragma unroll
  for (int k = 0; k < TOPK; ++k) ins4tie(ov[k], oi[k], tv, ti4);
  if ((tid & 1) == 0) {
    size_t base = ((size_t)(row0 + rw) * NBLK + blockIdx.y) * TOPK;
#pragma unroll
    for (int k = 0; k < TOPK; ++k) { candv[base + k] = tv[k]; candi[base + k] = ti4[k]; }
  }
}

// ---------------- K8a: per-(row, chunk-of-48) serial top-8 (pure TLP) ----------
__global__ __launch_bounds__(256) void k_cmerge1(const float* __restrict__ candv,
                                                 const int* __restrict__ candi,
                                                 float* __restrict__ pv8,
                                                 int* __restrict__ pi8) {
  int gid = blockIdx.x * 256 + threadIdx.x;      // [0, 12288*8)
  int row = gid >> 3, chunk = gid & 7;
  size_t base = (size_t)row * (NBLK * TOPK) + chunk * 48;
  float tv[8]; int ti8[8];
#pragma unroll
  for (int k = 0; k < 8; ++k) { tv[k] = -3.0e38f; ti8[k] = 0; }
  for (int i = 0; i < 48; ++i) ins8tie(candv[base + i], candi[base + i], tv, ti8);
  size_t ob = (size_t)gid * 8;
#pragma unroll
  for (int k = 0; k < 8; ++k) { pv8[ob + k] = tv[k]; pi8[ob + k] = ti8[k]; }
}

// ---------------- K8b: per-row merge of 8 partials + self-sentinel -------------
__global__ __launch_bounds__(256) void k_cmerge2(const float* __restrict__ pv8,
                                                 const int* __restrict__ pi8,
                                                 float* __restrict__ fv8,
                                                 int* __restrict__ fi8) {
  int row = blockIdx.x * 256 + threadIdx.x;      // [0, 12288)
  size_t base = (size_t)row * 64;
  float tv[8]; int ti8[8];
#pragma unroll
  for (int k = 0; k < 8; ++k) { tv[k] = -3.0e38f; ti8[k] = 0; }
  for (int i = 0; i < 64; ++i) ins8tie(pv8[base + i], pi8[base + i], tv, ti8);
  ins8tie(3.0e38f, row, tv, ti8);                // self-sentinel
  size_t ob = (size_t)row * 8;
#pragma unroll
  for (int k = 0; k < 8; ++k) { fv8[ob + k] = tv[k]; fi8[ob + k] = ti8[k]; }
}

// ---------------- K8c: exact fp32 rerank of final 8 (one wave per row) ---------
__global__ __launch_bounds__(256) void k_exact(const int* __restrict__ fi8,
                                               const float* __restrict__ h,
                                               const float* __restrict__ sq,
                                               const float* __restrict__ q,
                                               const float* __restrict__ tempP,
                                               float* __restrict__ out_idx,
                                               float* __restrict__ out_rows,
                                               float* __restrict__ out_vals) {
  const int tid = threadIdx.x;
  const int row = blockIdx.x * 4 + (tid >> 6);
  const int l = tid & 63;
  const float T = tempP[0];
  int ti8[8];
#pragma unroll
  for (int k = 0; k < 8; ++k) ti8[k] = fi8[(size_t)row * 8 + k];
  float4 hr = *(const float4*)&h[(size_t)row * D + l * 4];
  float lqe[8];
#pragma unroll
  for (int k = 0; k < 8; ++k) {
    int c = ti8[k];
    float4 hc = *(const float4*)&h[(size_t)c * D + l * 4];
    float p = fmaf(hr.x, hc.x, 0.0f);
    p = fmaf(hr.y, hc.y, p);
    p = fmaf(hr.z, hc.z, p);
    p = fmaf(hr.w, hc.w, p);
#pragma unroll
    for (int m = 1; m < 64; m <<= 1) p += __shfl_xor(p, m);
    float d2 = fmaxf(__fsub_rn(__fadd_rn(sq[row], sq[c]), __fmul_rn(2.0f, p)), 0.0f);
    float lp = -__fmul_rn(T, d2);
    float gg = logf(-logf(__fadd_rn(q[(size_t)row * N_NODES + c], 1e-8f)));
    lqe[k] = __fsub_rn(lp, gg);
  }
  float bv[TOPK]; int bi[TOPK];
#pragma unroll
  for (int k = 0; k < TOPK; ++k) { bv[k] = -3.0e38f; bi[k] = 0; }
#pragma unroll
  for (int k = 0; k < 8; ++k) {   // dedupe guard (sentinel + organic self)
    bool dup = false;
#pragma unroll
    for (int k2 = 0; k2 < 8; ++k2)
      if (k2 < k) dup = dup || (ti8[k2] == ti8[k]);
    if (!dup) ins4tie(lqe[k], ti8[k], bv, bi);
  }
  if (l == 0) {
#pragma unroll
    for (int k = 0; k < TOPK; ++k) {
      out_idx[(size_t)row * TOPK + k] = (float)bi[k];
      out_rows[(size_t)row * TOPK + k] = (float)row;
      out_vals[(size_t)row * TOPK + k] = bv[k];
    }
  }
}

// ---------------- launcher ----------------
extern "C" void kernel_launch(void* const* d_in, const int* in_sizes, int n_in,
                              void* d_out, int out_size, void* d_ws, size_t ws_size,
                              hipStream_t stream) {
  const float* x = nullptr;     // 3145728
  const float* W = nullptr;     // 65536
  const float* b = nullptr;     // 256
  const float* temp = nullptr;  // 1
  const float* q = nullptr;     // 150994944
  const int* ei = nullptr;      // 393216
  for (int i = 0; i < n_in; ++i) {
    switch (in_sizes[i]) {
      case 3145728:   x = (const float*)d_in[i]; break;
      case 65536:     W = (const float*)d_in[i]; break;
      case 256:       b = (const float*)d_in[i]; break;
      case 1:         temp = (const float*)d_in[i]; break;
      case 150994944: q = (const float*)d_in[i]; break;
      case 393216:    ei = (const int*)d_in[i]; break;
      default: break;
    }
  }
  if (!x || !W || !b || !temp || !q || !ei) return;

  float* out = (float*)d_out;
  float* out_h = out;                                  // [0, 3145728)
  float* out_idx = out + (size_t)N_NODES * D;          // [3145728, 3194880)
  float* out_rows = out_idx + (size_t)N_NODES * TOPK;  // [3194880, 3244032)
  float* out_vals = out_rows + (size_t)N_NODES * TOPK; // [3244032, 3293184)

  char* ws = (char*)d_ws;
  size_t off = 0;
  auto alloc = [&](size_t bytes) {
    char* p = ws + off;
    off += (bytes + 255) & ~(size_t)255;
    return p;
  };
  float* XW = (float*)alloc((size_t)N_NODES * D * 4);  // reused as hhi/hlo after k_agg
  int* deg = (int*)alloc((size_t)N_NODES * 4);
  int* rs = (int*)alloc((size_t)N_NODES * 4);
  int* cur = (int*)alloc((size_t)N_NODES * 4);
  float* dinv = (float*)alloc((size_t)N_NODES * 4);
  float* sq = (float*)alloc((size_t)N_NODES * 4);
  int* ecol = (int*)alloc((size_t)NE * 4);
  int* eeid = (int*)alloc((size_t)NE * 4);
  float* candv = (float*)alloc((size_t)N_NODES * NBLK * TOPK * 4);  // 18.9 MB
  int* candi = (int*)alloc((size_t)N_NODES * NBLK * TOPK * 4);      // 18.9 MB
  float* pv8 = (float*)alloc((size_t)N_NODES * 64 * 4);             // 3.1 MB
  int* pi8 = (int*)alloc((size_t)N_NODES * 64 * 4);                 // 3.1 MB
  float* fv8 = (float*)alloc((size_t)N_NODES * 8 * 4);              // 0.4 MB
  int* fi8 = (int*)alloc((size_t)N_NODES * 8 * 4);                  // 0.4 MB
  if (off > ws_size) return;  // loud zero-output beacon if ws too small

  hipMemsetAsync(deg, 0, (size_t)N_NODES * 4, stream);
  hipMemsetAsync(cur, 0, (size_t)N_NODES * 4, stream);

  k_xw<<<dim3(N_NODES / 64, D / 64), 256, 0, stream>>>(x, W, XW);
  k_deg<<<NE / 256, 256, 0, stream>>>(ei, deg);
  k_scan<<<1, 256, 0, stream>>>(deg, rs, dinv);
  k_fill<<<NE / 256, 256, 0, stream>>>(ei, ei + NE, rs, cur, ecol, eeid);
  k_agg<<<N_NODES, 256, 0, stream>>>(XW, b, deg, rs, ecol, eeid, dinv, out_h, sq);

  // XW dead -> reuse as bf16 hi/lo arrays (exact fit: N*D*2B*2 = N*D*4B)
  unsigned short* hhi = (unsigned short*)XW;
  unsigned short* hlo = hhi + (size_t)N_NODES * D;
  k_split<<<(N_NODES * D) / 256, 256, 0, stream>>>(out_h, hhi, hlo);
  k_gemm<<<dim3(NBLK, NBLK), 256, 0, stream>>>(hhi, hlo, sq, q, temp, candv, candi);
  k_cmerge1<<<(N_NODES * 8) / 256, 256, 0, stream>>>(candv, candi, pv8, pi8);
  k_cmerge2<<<N_NODES / 256, 256, 0, stream>>>(pv8, pi8, fv8, fi8);
  k_exact<<<N_NODES / 4, 256, 0, stream>>>(fi8, out_h, sq, q, temp,
                                           out_idx, out_rows, out_vals);
}